// Round 10
// baseline (1579.104 us; speedup 1.0000x reference)
//
#include <hip/hip_runtime.h>
#include <hip/hip_bf16.h>

#define NNODES 100000
#define HIDC 256
#define NFEAT 9
#define VOCABS 128
#define BFD 128        // bases output dim
#define NCOMB 96       // heads*bases*aggs
#define NGR 5000
#define LAYERSN 4
#define EPSV 1e-5f
#define SCHUNK 1024    // scan chunk
#define NPP 16         // nodes per block in pooling
#define NTILES 14      // 224/16 output tiles (8 bases + 6 comb)
#define AGGBLK 2048    // agg grid (8192 waves = 32 waves/CU)
#define AGGW (AGGBLK * 4)
#define PBL (NTILES * 8 * 64)   // B fragments per layer
#define NBUK 32        // scatter buckets
#define BDIV 3125      // nodes per bucket
#define SC2K 16        // blocks per bucket in pass B

typedef __hip_bfloat16 bf16;
typedef __attribute__((ext_vector_type(8))) short sh8;
typedef __attribute__((ext_vector_type(4))) float fx4;

__device__ __forceinline__ float b2f(bf16 v) { return __bfloat162float(v); }
__device__ __forceinline__ bf16 f2b(float v) { return __float2bfloat16(v); }
__device__ __forceinline__ float ldf(const float* p) { return *p; }
__device__ __forceinline__ float ldf(const bf16* p) { return b2f(*p); }
__device__ __forceinline__ void stf(float* p, float v) { *p = v; }
__device__ __forceinline__ void stf(bf16* p, float v) { *p = f2b(v); }

__device__ __forceinline__ unsigned pack2bf(float a, float b) {
    unsigned ua = __float_as_uint(a), ub = __float_as_uint(b);
    ua = (ua + 0x7FFFu + ((ua >> 16) & 1u)) >> 16;
    ub = (ub + 0x7FFFu + ((ub >> 16) & 1u)) >> 16;
    return ua | (ub << 16);
}

// 0. sentinel
__global__ __launch_bounds__(256) void k_sentinel(float* out, int n, float val) {
    int i = blockIdx.x * 256 + threadIdx.x;
    if (i < n) out[i] = val;
}

// 1. AtomEncoder
template <typename TH>
__global__ __launch_bounds__(256) void k_atom(const int* __restrict__ x,
                                              const float* __restrict__ emb,
                                              TH* __restrict__ h) {
    int n = blockIdx.x;
    __shared__ int xs[NFEAT];
    if (threadIdx.x < NFEAT) xs[threadIdx.x] = x[n * NFEAT + threadIdx.x];
    __syncthreads();
    int c = threadIdx.x;
    float acc = 0.f;
#pragma unroll
    for (int f = 0; f < NFEAT; ++f)
        acc += emb[(f * VOCABS + xs[f]) * HIDC + c];
    stf(&h[(size_t)n * HIDC + c], acc);
}

// 2a. histogram of dst
__global__ __launch_bounds__(256) void k_hist(const int* __restrict__ dst,
                                              int* __restrict__ counts, int E) {
    int e = blockIdx.x * 256 + threadIdx.x;
    if (e < E) atomicAdd(&counts[dst[e]], 1);
}

__global__ __launch_bounds__(256) void k_scansum(const int* __restrict__ counts,
                                                 int* __restrict__ btot, int n) {
    __shared__ int sh[256];
    int b = blockIdx.x, t = threadIdx.x;
    int base = b * SCHUNK;
    int s = 0;
#pragma unroll
    for (int k = 0; k < 4; ++k) {
        int i = base + t + k * 256;
        if (i < n) s += counts[i];
    }
    sh[t] = s;
    __syncthreads();
    for (int st = 128; st > 0; st >>= 1) {
        if (t < st) sh[t] += sh[t + st];
        __syncthreads();
    }
    if (t == 0) btot[b] = sh[0];
}

__global__ void k_scansmall(const int* __restrict__ btot, int* __restrict__ boff, int nb) {
    if (threadIdx.x == 0 && blockIdx.x == 0) {
        int a = 0;
        for (int i = 0; i < nb; ++i) { boff[i] = a; a += btot[i]; }
    }
}

// 2b-3. per-chunk scan -> rowptr AND cursor
__global__ __launch_bounds__(256) void k_scanapply(const int* __restrict__ counts,
                                                   const int* __restrict__ boff,
                                                   int* __restrict__ rowptr,
                                                   int* __restrict__ cursor, int n) {
    __shared__ int sh[256];
    int b = blockIdx.x, t = threadIdx.x;
    int base = b * SCHUNK + t * 4;
    int c0 = (base + 0 < n) ? counts[base + 0] : 0;
    int c1 = (base + 1 < n) ? counts[base + 1] : 0;
    int c2 = (base + 2 < n) ? counts[base + 2] : 0;
    int c3 = (base + 3 < n) ? counts[base + 3] : 0;
    int s0 = c0, s1 = s0 + c1, s2 = s1 + c2, s3 = s2 + c3;
    sh[t] = s3;
    __syncthreads();
    for (int st = 1; st < 256; st <<= 1) {
        int v = (t >= st) ? sh[t - st] : 0;
        __syncthreads();
        sh[t] += v;
        __syncthreads();
    }
    int excl = sh[t] - s3 + boff[b];
    if (base + 0 < n) { rowptr[base + 1] = excl + s0; cursor[base + 0] = excl; }
    if (base + 1 < n) { rowptr[base + 2] = excl + s1; cursor[base + 1] = excl + s0; }
    if (base + 2 < n) { rowptr[base + 3] = excl + s2; cursor[base + 2] = excl + s1; }
    if (base + 3 < n) { rowptr[base + 4] = excl + s3; cursor[base + 3] = excl + s2; }
    if (b == 0 && t == 0) rowptr[0] = 0;
}

// 2e. bucket cursors = rowptr at bucket boundaries
__global__ void k_binit(const int* __restrict__ rowptr, int* __restrict__ gcur) {
    int b = threadIdx.x;
    if (b < NBUK) gcur[b] = rowptr[b * BDIV];
}

// 2f. pass A: partition edges into ebuf by dst bucket (localized writes)
__global__ __launch_bounds__(256) void k_bucket(const int* __restrict__ src,
                                                const int* __restrict__ dst,
                                                int* __restrict__ gcur,
                                                uint2* __restrict__ ebuf, int E) {
    __shared__ int cnt[NBUK], base[NBUK], off[NBUK];
    int tid = threadIdx.x;
    if (tid < NBUK) { cnt[tid] = 0; off[tid] = 0; }
    __syncthreads();
    int d[4], s[4], bk[4];
    int e0 = blockIdx.x * 1024;
#pragma unroll
    for (int k = 0; k < 4; ++k) {
        int e = e0 + tid + k * 256;
        if (e < E) {
            d[k] = dst[e]; s[k] = src[e];
            bk[k] = d[k] / BDIV;
            atomicAdd(&cnt[bk[k]], 1);
        } else bk[k] = -1;
    }
    __syncthreads();
    if (tid < NBUK && cnt[tid] > 0) base[tid] = atomicAdd(&gcur[tid], cnt[tid]);
    __syncthreads();
#pragma unroll
    for (int k = 0; k < 4; ++k) {
        if (bk[k] >= 0) {
            int sl = base[bk[k]] + atomicAdd(&off[bk[k]], 1);
            ebuf[sl] = make_uint2((unsigned)d[k], (unsigned)s[k]);
        }
    }
}

// 2g. pass B: scatter within buckets; blockIdx%NBUK = bucket -> XCD affinity
__global__ __launch_bounds__(256) void k_scatter2(const uint2* __restrict__ ebuf,
                                                  const int* __restrict__ rowptr,
                                                  int* __restrict__ cursor,
                                                  int* __restrict__ csr) {
    int bk = blockIdx.x & (NBUK - 1);
    int chunk = blockIdx.x >> 5;
    int lo = rowptr[bk * BDIV];
    int nhi = (bk + 1) * BDIV; if (nhi > NNODES) nhi = NNODES;
    int hi = rowptr[nhi];
    for (int e = lo + chunk * 256 + threadIdx.x; e < hi; e += SC2K * 256) {
        uint2 p = ebuf[e];
        int pos = atomicAdd(&cursor[p.x], 1);
        csr[pos] = (int)p.y;
    }
}

// 3a. pack W of ALL layers into MFMA B-fragment order
__global__ __launch_bounds__(256) void k_packB4(const float* __restrict__ basesW,
                                                const float* __restrict__ combW,
                                                bf16* __restrict__ Bp4) {
    int tid = blockIdx.x * 256 + threadIdx.x;
    if (tid >= LAYERSN * PBL) return;
    int layer = tid / PBL;
    int rem = tid % PBL;
    int l = rem & 63;
    int q = (rem >> 6) & 7;
    int t = rem >> 9;
    int n = t * 16 + (l & 15);
    int k0 = q * 32 + (l >> 4) * 8;
    const float* Wb = basesW + (size_t)layer * HIDC * BFD;
    const float* Wc = combW + (size_t)layer * HIDC * NCOMB;
    short out[8];
#pragma unroll
    for (int i = 0; i < 8; ++i) {
        int k = k0 + i;
        float v = (n < BFD) ? Wb[k * BFD + n] : Wc[k * NCOMB + (n - BFD)];
        unsigned u = __float_as_uint(v);
        out[i] = (short)((u + 0x7FFFu + ((u >> 16) & 1u)) >> 16);
    }
    *(sh8*)(Bp4 + (size_t)tid * 8) = *(sh8*)out;
}

// 3b. MFMA node GEMM (64 rows/block, 4 waves) + optional fused prev-layer apply
template <typename TH, typename TW>
__global__ __launch_bounds__(256) void k_gemm_mfma(TH* __restrict__ h,
                                                   const bf16* __restrict__ Bp,
                                                   const float* __restrict__ cb,
                                                   bf16* __restrict__ bases,
                                                   TW* __restrict__ wco,
                                                   const bf16* __restrict__ convp,
                                                   const float* __restrict__ ss) {
    __shared__ unsigned ldsA[8192];
    int tid = threadIdx.x;
    size_t blk = blockIdx.x;
#pragma unroll 4
    for (int it = 0; it < 32; ++it) {
        int p = tid + it * 256;
        int row = p >> 7, cp = p & 127;
        size_t rg = blk * 64 + row;
        unsigned word = 0;
        if (rg < NNODES) {
            int c0 = cp * 2;
            float a0 = ldf(&h[rg * HIDC + c0]);
            float a1 = ldf(&h[rg * HIDC + c0 + 1]);
            if (convp) {
                float v0 = b2f(convp[rg * HIDC + c0]) * ss[c0] + ss[HIDC + c0];
                float v1 = b2f(convp[rg * HIDC + c0 + 1]) * ss[c0 + 1] + ss[HIDC + c0 + 1];
                a0 += fmaxf(v0, 0.f);
                a1 += fmaxf(v1, 0.f);
                stf(&h[rg * HIDC + c0], a0);
                stf(&h[rg * HIDC + c0 + 1], a1);
            }
            word = pack2bf(a0, a1);
        }
        ldsA[(row * 128 + cp) ^ ((row & 7) << 2)] = word;
    }
    __syncthreads();
    int w = tid >> 6, l = tid & 63;
    int r = 16 * w + (l & 15);
    sh8 af[8];
    const char* lb = (const char*)ldsA;
#pragma unroll
    for (int q = 0; q < 8; ++q) {
        int byte = (r * 512 + q * 64 + (l >> 4) * 16) ^ ((r & 7) << 4);
        af[q] = *(const sh8*)(lb + byte);
    }
    fx4 acc[NTILES];
#pragma unroll
    for (int t = 0; t < NTILES; ++t) acc[t] = (fx4){0.f, 0.f, 0.f, 0.f};
    const sh8* bp8 = (const sh8*)Bp;
#pragma unroll
    for (int t = 0; t < NTILES; ++t) {
#pragma unroll
        for (int q = 0; q < 8; ++q) {
            acc[t] = __builtin_amdgcn_mfma_f32_16x16x32_bf16(
                af[q], bp8[(t * 8 + q) * 64 + l], acc[t], 0, 0, 0);
        }
    }
#pragma unroll
    for (int t = 0; t < NTILES; ++t) {
#pragma unroll
        for (int j = 0; j < 4; ++j) {
            int rl = 16 * w + (l >> 4) * 4 + j;
            size_t rg = blk * 64 + rl;
            if (rg >= NNODES) continue;
            if (t < 8) {
                int col = t * 16 + (l & 15);
                bases[rg * BFD + col] = f2b(acc[t][j]);
            } else {
                int col = (t - 8) * 16 + (l & 15);
                stf(&wco[rg * NCOMB + col], acc[t][j] + cb[col]);
            }
        }
    }
}

// 4. CSR aggregation + einsum + fused BN-stat partials.
//    WAVE-INDEPENDENT: each wave owns its node end-to-end; no barriers in loop.
template <typename TW>
__global__ __launch_bounds__(256) void k_agg(const int* __restrict__ rowptr,
                                             const int* __restrict__ csr,
                                             const uint2* __restrict__ b2,
                                             const TW* __restrict__ wco,
                                             const float* __restrict__ bias,
                                             bf16* __restrict__ conv,
                                             float* __restrict__ partials) {
    __shared__ float agg[4][3][BFD];
    __shared__ float red[512];
    int tid = threadIdx.x;
    int wv = tid >> 6, lane = tid & 63;
    int cl = lane & 31;
    bool loh = lane < 32;
    red[tid] = 0.f;
    red[tid + 256] = 0.f;
    __syncthreads();
    int hh = lane >> 3;                       // out-channel group (const per lane)
    float bb[4];
#pragma unroll
    for (int j = 0; j < 4; ++j) bb[j] = bias[4 * lane + j];
    float sts[4] = {0.f, 0.f, 0.f, 0.f}, sts2[4] = {0.f, 0.f, 0.f, 0.f};
    for (int n = blockIdx.x * 4 + wv; n < NNODES; n += AGGW) {
        int r0 = rowptr[n], r1 = rowptr[n + 1];
        float s0 = 0.f, s1 = 0.f, s2 = 0.f, s3 = 0.f;
        float m0 = -INFINITY, m1 = -INFINITY, m2 = -INFINITY, m3 = -INFINITY;
        int e = r0;
#define ACCU2(v) { float f0 = __uint_as_float((v).x << 16);            \
                   float f1 = __uint_as_float((v).x & 0xFFFF0000u);    \
                   float f2 = __uint_as_float((v).y << 16);            \
                   float f3 = __uint_as_float((v).y & 0xFFFF0000u);    \
                   s0 += f0; s1 += f1; s2 += f2; s3 += f3;             \
                   m0 = fmaxf(m0, f0); m1 = fmaxf(m1, f1);             \
                   m2 = fmaxf(m2, f2); m3 = fmaxf(m3, f3); }
        for (; e + 4 <= r1; e += 4) {
            int sa = loh ? csr[e + 0] : csr[e + 1];
            int sb = loh ? csr[e + 2] : csr[e + 3];
            uint2 va = b2[(size_t)sa * 32 + cl];
            uint2 vb = b2[(size_t)sb * 32 + cl];
            ACCU2(va) ACCU2(vb)
        }
        for (; e + 2 <= r1; e += 2) {
            int sa = loh ? csr[e + 0] : csr[e + 1];
            uint2 va = b2[(size_t)sa * 32 + cl];
            ACCU2(va)
        }
        if (e < r1 && loh) {
            uint2 va = b2[(size_t)csr[e] * 32 + cl];
            ACCU2(va)
        }
#undef ACCU2
        // combine half-wave partials (edge split), write wave-local agg
        float t0 = s0 + __shfl_xor(s0, 32);
        float t1 = s1 + __shfl_xor(s1, 32);
        float t2 = s2 + __shfl_xor(s2, 32);
        float t3 = s3 + __shfl_xor(s3, 32);
        float x0 = fmaxf(m0, __shfl_xor(m0, 32));
        float x1 = fmaxf(m1, __shfl_xor(m1, 32));
        float x2 = fmaxf(m2, __shfl_xor(m2, 32));
        float x3 = fmaxf(m3, __shfl_xor(m3, 32));
        if (loh) {
            float inv = 1.0f / (float)(r1 - r0);
            int cc = 4 * cl;
            agg[wv][0][cc + 0] = t0; agg[wv][1][cc + 0] = t0 * inv; agg[wv][2][cc + 0] = x0;
            agg[wv][0][cc + 1] = t1; agg[wv][1][cc + 1] = t1 * inv; agg[wv][2][cc + 1] = x1;
            agg[wv][0][cc + 2] = t2; agg[wv][1][cc + 2] = t2 * inv; agg[wv][2][cc + 2] = x2;
            agg[wv][0][cc + 3] = t3; agg[wv][1][cc + 3] = t3 * inv; agg[wv][2][cc + 3] = x3;
        }
        // wave-local einsum: lane computes channels 4*lane..4*lane+3
        const TW* wp = &wco[(size_t)n * NCOMB + hh * 12];
        float w[12];
#pragma unroll
        for (int k = 0; k < 12; ++k) w[k] = ldf(&wp[k]);
        float o[4];
#pragma unroll
        for (int j = 0; j < 4; ++j) {
            int d = (4 * lane + j) & 31;
            float a = 0.f;
#pragma unroll
            for (int b = 0; b < 4; ++b) {
                a += w[b] * agg[wv][0][b * 32 + d];
                a += w[4 + b] * agg[wv][1][b * 32 + d];
                a += w[8 + b] * agg[wv][2][b * 32 + d];
            }
            a += bb[j];
            o[j] = a;
            sts[j] += a;
            sts2[j] += a * a;
        }
        uint2 cv = make_uint2(pack2bf(o[0], o[1]), pack2bf(o[2], o[3]));
        ((uint2*)conv)[(size_t)n * 64 + lane] = cv;
    }
    // block-level stats reduce (single barrier)
#pragma unroll
    for (int j = 0; j < 4; ++j) {
        atomicAdd(&red[4 * lane + j], sts[j]);
        atomicAdd(&red[256 + 4 * lane + j], sts2[j]);
    }
    __syncthreads();
    partials[(size_t)blockIdx.x * 512 + tid] = red[tid];
    partials[(size_t)blockIdx.x * 512 + 256 + tid] = red[tid + 256];
}

// 4b. reduce partials -> sums[512]
__global__ __launch_bounds__(256) void k_redstats(const float* __restrict__ partials,
                                                  float* __restrict__ sums) {
    int g = blockIdx.x * 256 + threadIdx.x;
    int j = g & 511;
    int chunk = g >> 9;
    float s = 0.f;
    for (int pb = chunk * 256; pb < (chunk + 1) * 256; ++pb)
        s += partials[(size_t)pb * 512 + j];
    atomicAdd(&sums[j], s);
}

// 6. BN finalize
template <int C>
__global__ void k_bnfin(const float* __restrict__ sums, const float* __restrict__ g,
                        const float* __restrict__ b, float nrows, float* __restrict__ ss) {
    int c = threadIdx.x;
    float mu = sums[c] / nrows;
    float var = sums[C + c] / nrows - mu * mu;
    float rstd = rsqrtf(fmaxf(var, 0.f) + EPSV);
    float sc = rstd * g[c];
    ss[c] = sc;
    ss[C + c] = b[c] - mu * sc;
}

// 7. BN apply + ReLU + residual into h (final layer only)
template <typename TH>
__global__ __launch_bounds__(256) void k_apply_res(const bf16* __restrict__ conv,
                                                   const float* __restrict__ ss,
                                                   TH* __restrict__ h) {
    int n = blockIdx.x;
    int c = threadIdx.x;
    float v = b2f(conv[(size_t)n * HIDC + c]) * ss[c] + ss[HIDC + c];
    size_t i = (size_t)n * HIDC + c;
    stf(&h[i], ldf(&h[i]) + fmaxf(v, 0.f));
}

// 8. pooling (sorted batch)
template <typename TH>
__global__ __launch_bounds__(256) void k_pool(const TH* __restrict__ h,
                                              const int* __restrict__ batch,
                                              float* __restrict__ gs,
                                              float* __restrict__ cnt) {
    int c = threadIdx.x;
    int n0 = blockIdx.x * NPP;
    int end = min(n0 + NPP, NNODES);
    float acc = 0.f, ccnt = 0.f;
    int cur = batch[n0];
    for (int n = n0; n < end; ++n) {
        int b = batch[n];
        if (b != cur) {
            atomicAdd(&gs[(size_t)cur * HIDC + c], acc);
            if (c == 0) atomicAdd(&cnt[cur], ccnt);
            acc = 0.f; ccnt = 0.f; cur = b;
        }
        acc += ldf(&h[(size_t)n * HIDC + c]);
        ccnt += 1.f;
    }
    atomicAdd(&gs[(size_t)cur * HIDC + c], acc);
    if (c == 0) atomicAdd(&cnt[cur], ccnt);
}

__global__ __launch_bounds__(256) void k_pooldiv(float* __restrict__ gs,
                                                 const float* __restrict__ cnt) {
    int i = blockIdx.x * 256 + threadIdx.x;
    if (i >= NGR * HIDC) return;
    int ng = i >> 8;
    gs[i] = gs[i] / fmaxf(cnt[ng], 1.0f);
}

// 9. head row-GEMM
template <int K, int C>
__global__ void k_rowgemm(const float* __restrict__ in, const float* __restrict__ W,
                          float* __restrict__ out) {
    int r = blockIdx.x;
    __shared__ float rs[K];
    for (int i = threadIdx.x; i < K; i += C) rs[i] = in[r * K + i];
    __syncthreads();
    int c = threadIdx.x;
    float acc = 0.f;
    for (int k = 0; k < K; ++k) acc += rs[k] * W[k * C + c];
    out[r * C + c] = acc;
}

// 10. head BN stats
template <int C>
__global__ void k_stats(const float* __restrict__ a, int rows, int rpb,
                        float* __restrict__ sums) {
    int c = threadIdx.x;
    int r0 = blockIdx.x * rpb;
    int r1 = min(r0 + rpb, rows);
    float s = 0.f, s2 = 0.f;
    for (int r = r0; r < r1; ++r) {
        float v = a[r * C + c];
        s += v;
        s2 += v * v;
    }
    atomicAdd(&sums[c], s);
    atomicAdd(&sums[C + c], s2);
}

// 11. head BN apply + ReLU
template <int C>
__global__ void k_apply_relu(float* __restrict__ a, const float* __restrict__ ss, int rows) {
    int i = blockIdx.x * 256 + threadIdx.x;
    if (i >= rows * C) return;
    int c = i % C;
    float v = a[i] * ss[c] + ss[C + c];
    a[i] = fmaxf(v, 0.f);
}

// 12. final linear
__global__ __launch_bounds__(256) void k_final(const float* __restrict__ g2,
                                               const float* __restrict__ w3,
                                               const float* __restrict__ b3,
                                               float* __restrict__ out) {
    int r = blockIdx.x * 256 + threadIdx.x;
    if (r >= NGR) return;
    float acc = 0.f;
#pragma unroll
    for (int k = 0; k < 64; ++k) acc += g2[r * 64 + k] * w3[k];
    out[r] = acc + b3[0];
}

static inline size_t alignup(size_t v) { return (v + 255) & ~(size_t)255; }

template <typename TH, typename TW>
static size_t carve_need(int E) {
    size_t off = 0;
    off = alignup(off + (size_t)NNODES * HIDC * sizeof(TH));   // h
    off = alignup(off + (size_t)NNODES * BFD * 2);             // bases bf16
    off = alignup(off + (size_t)NNODES * NCOMB * sizeof(TW));  // wco
    off = alignup(off + (size_t)NNODES * HIDC * 2);            // conv bf16
    off = alignup(off + (size_t)(NNODES + 1) * 4);             // rowptr
    off = alignup(off + (size_t)NNODES * 4);                   // cursor
    off = alignup(off + (size_t)E * 4);                        // csr
    off = alignup(off + (size_t)E * 8);                        // ebuf
    off = alignup(off + 2 * HIDC * 4);                         // sums
    off = alignup(off + 2 * HIDC * 4);                         // ss
    off = alignup(off + 256 * 4);                              // btot
    off = alignup(off + 256 * 4);                              // boff
    off = alignup(off + 256 * 4);                              // gcur
    off = alignup(off + (size_t)LAYERSN * PBL * 8 * 2);        // Bp4
    off = alignup(off + (size_t)AGGBLK * 512 * 4);             // partials
    return off;  // pool/head alias conv region (6.8 MB < 51.2 MB)
}

template <typename TH, typename TW>
static void run_all(const int* x, const int* esrc, const int* edst, const int* batch,
                    const float* emb, const float* basesW, const float* combW,
                    const float* combB, const float* convB, const float* bnG,
                    const float* bnB, const float* w1, const float* bn1g,
                    const float* bn1b, const float* w2, const float* bn2g,
                    const float* bn2b, const float* w3, const float* b3, int E,
                    float* out, char* base, hipStream_t stream) {
    size_t off = 0;
    TH* h = (TH*)(base + off);       off = alignup(off + (size_t)NNODES * HIDC * sizeof(TH));
    bf16* bases = (bf16*)(base + off); off = alignup(off + (size_t)NNODES * BFD * 2);
    TW* wco = (TW*)(base + off);     off = alignup(off + (size_t)NNODES * NCOMB * sizeof(TW));
    size_t o_conv = off;
    bf16* conv = (bf16*)(base + off); off = alignup(off + (size_t)NNODES * HIDC * 2);
    int* rowptr = (int*)(base + off); off = alignup(off + (size_t)(NNODES + 1) * 4);
    int* cursor = (int*)(base + off); off = alignup(off + (size_t)NNODES * 4);
    int* csr = (int*)(base + off);    off = alignup(off + (size_t)E * 4);
    uint2* ebuf = (uint2*)(base + off); off = alignup(off + (size_t)E * 8);
    float* sums = (float*)(base + off); off = alignup(off + 2 * HIDC * 4);
    float* ss = (float*)(base + off);   off = alignup(off + 2 * HIDC * 4);
    int* btot = (int*)(base + off);     off = alignup(off + 256 * 4);
    int* boff = (int*)(base + off);     off = alignup(off + 256 * 4);
    int* gcur = (int*)(base + off);     off = alignup(off + 256 * 4);
    bf16* Bp4 = (bf16*)(base + off);    off = alignup(off + (size_t)LAYERSN * PBL * 8 * 2);
    float* partials = (float*)(base + off); off = alignup(off + (size_t)AGGBLK * 512 * 4);
    size_t po = o_conv;
    float* gs = (float*)(base + po);  po = alignup(po + (size_t)NGR * HIDC * 4);
    float* cnt = (float*)(base + po); po = alignup(po + (size_t)NGR * 4);
    float* r1 = (float*)(base + po);  po = alignup(po + (size_t)NGR * 128 * 4);
    float* r2 = (float*)(base + po);  po = alignup(po + (size_t)NGR * 64 * 4);

    const int NB = (NNODES + SCHUNK - 1) / SCHUNK;  // 98
    const int GEMMBLK = (NNODES + 63) / 64;         // 1563

    // once: embeddings + CSR build (bucketed) + all-layer weight pack
    k_atom<TH><<<NNODES, 256, 0, stream>>>(x, emb, h);
    k_packB4<<<(LAYERSN * PBL + 255) / 256, 256, 0, stream>>>(basesW, combW, Bp4);
    hipMemsetAsync(cursor, 0, (size_t)NNODES * 4, stream);
    k_hist<<<(E + 255) / 256, 256, 0, stream>>>(edst, cursor, E);
    k_scansum<<<NB, 256, 0, stream>>>(cursor, btot, NNODES);
    k_scansmall<<<1, 64, 0, stream>>>(btot, boff, NB);
    k_scanapply<<<NB, 256, 0, stream>>>(cursor, boff, rowptr, cursor, NNODES);
    k_binit<<<1, NBUK, 0, stream>>>(rowptr, gcur);
    k_bucket<<<(E + 1023) / 1024, 256, 0, stream>>>(esrc, edst, gcur, ebuf, E);
    k_scatter2<<<NBUK * SC2K, 256, 0, stream>>>(ebuf, rowptr, cursor, csr);

    for (int l = 0; l < LAYERSN; ++l) {
        hipMemsetAsync(sums, 0, 2 * HIDC * 4, stream);
        k_gemm_mfma<TH, TW><<<GEMMBLK, 256, 0, stream>>>(
            h, Bp4 + (size_t)l * PBL * 8, combB + (size_t)l * NCOMB, bases, wco,
            (l > 0) ? conv : (const bf16*)nullptr, ss);
        k_agg<TW><<<AGGBLK, 256, 0, stream>>>(rowptr, csr, (const uint2*)bases,
                                              wco, convB + (size_t)l * HIDC, conv,
                                              partials);
        k_redstats<<<16, 256, 0, stream>>>(partials, sums);
        k_bnfin<HIDC><<<1, HIDC, 0, stream>>>(sums, bnG + (size_t)l * HIDC,
                                              bnB + (size_t)l * HIDC, (float)NNODES, ss);
    }
    k_apply_res<TH><<<NNODES, 256, 0, stream>>>(conv, ss, h);

    hipMemsetAsync(gs, 0, (size_t)NGR * HIDC * 4, stream);
    hipMemsetAsync(cnt, 0, (size_t)NGR * 4, stream);
    k_pool<TH><<<(NNODES + NPP - 1) / NPP, 256, 0, stream>>>(h, batch, gs, cnt);
    k_pooldiv<<<(NGR * HIDC + 255) / 256, 256, 0, stream>>>(gs, cnt);

    k_rowgemm<256, 128><<<NGR, 128, 0, stream>>>(gs, w1, r1);
    hipMemsetAsync(sums, 0, 2 * 128 * 4, stream);
    k_stats<128><<<(NGR + 15) / 16, 128, 0, stream>>>(r1, NGR, 16, sums);
    k_bnfin<128><<<1, 128, 0, stream>>>(sums, bn1g, bn1b, (float)NGR, ss);
    k_apply_relu<128><<<(NGR * 128 + 255) / 256, 256, 0, stream>>>(r1, ss, NGR);

    k_rowgemm<128, 64><<<NGR, 64, 0, stream>>>(r1, w2, r2);
    hipMemsetAsync(sums, 0, 2 * 64 * 4, stream);
    k_stats<64><<<(NGR + 31) / 32, 64, 0, stream>>>(r2, NGR, 32, sums);
    k_bnfin<64><<<1, 64, 0, stream>>>(sums, bn2g, bn2b, (float)NGR, ss);
    k_apply_relu<64><<<(NGR * 64 + 255) / 256, 256, 0, stream>>>(r2, ss, NGR);

    k_final<<<(NGR + 255) / 256, 256, 0, stream>>>(r2, w3, b3, out);
}

extern "C" void kernel_launch(void* const* d_in, const int* in_sizes, int n_in,
                              void* d_out, int out_size, void* d_ws, size_t ws_size,
                              hipStream_t stream) {
    const int* x        = (const int*)d_in[0];
    const int* esrc     = (const int*)d_in[1];
    const int* edst     = (const int*)d_in[2];
    const int* batch    = (const int*)d_in[3];
    const float* emb    = (const float*)d_in[4];
    const float* basesW = (const float*)d_in[5];
    const float* combW  = (const float*)d_in[6];
    const float* combB  = (const float*)d_in[7];
    const float* convB  = (const float*)d_in[8];
    const float* bnG    = (const float*)d_in[9];
    const float* bnB    = (const float*)d_in[10];
    const float* w1     = (const float*)d_in[11];
    const float* bn1g   = (const float*)d_in[12];
    const float* bn1b   = (const float*)d_in[13];
    const float* w2     = (const float*)d_in[14];
    const float* bn2g   = (const float*)d_in[15];
    const float* bn2b   = (const float*)d_in[16];
    const float* w3     = (const float*)d_in[17];
    const float* b3     = (const float*)d_in[18];
    const int E = in_sizes[1];

    size_t need_full    = carve_need<float, float>(E);
    size_t need_compact = carve_need<bf16, bf16>(E);

    if (ws_size >= need_full) {
        run_all<float, float>(x, esrc, edst, batch, emb, basesW, combW, combB, convB,
                              bnG, bnB, w1, bn1g, bn1b, w2, bn2g, bn2b, w3, b3, E,
                              (float*)d_out, (char*)d_ws, stream);
    } else if (ws_size >= need_compact) {
        run_all<bf16, bf16>(x, esrc, edst, batch, emb, basesW, combW, combB, convB,
                            bnG, bnB, w1, bn1g, bn1b, w2, bn2g, bn2b, w3, b3, E,
                            (float*)d_out, (char*)d_ws, stream);
    } else {
        k_sentinel<<<(out_size + 255) / 256, 256, 0, stream>>>(
            (float*)d_out, out_size, (float)(ws_size >> 20));
    }
}

// Round 12
// 1416.044 us; speedup vs baseline: 1.1152x; 1.1152x over previous
//
#include <hip/hip_runtime.h>
#include <hip/hip_bf16.h>

#define NNODES 100000
#define HIDC 256
#define NFEAT 9
#define VOCABS 128
#define BFD 128        // bases output dim
#define NCOMB 96       // heads*bases*aggs
#define NGR 5000
#define LAYERSN 4
#define EPSV 1e-5f
#define SCHUNK 1024    // scan chunk
#define NPP 16         // nodes per block in pooling
#define NTILES 14      // 224/16 output tiles (8 bases + 6 comb)
#define AGGBLK 2048    // agg grid
#define PBL (NTILES * 8 * 64)   // B fragments per layer
#define NBUK 32        // scatter buckets
#define BDIV 3125      // nodes per bucket
#define SC2K 16        // blocks per bucket in pass B

typedef __hip_bfloat16 bf16;
typedef __attribute__((ext_vector_type(8))) short sh8;
typedef __attribute__((ext_vector_type(4))) float fx4;

__device__ __forceinline__ float b2f(bf16 v) { return __bfloat162float(v); }
__device__ __forceinline__ bf16 f2b(float v) { return __float2bfloat16(v); }
__device__ __forceinline__ float ldf(const float* p) { return *p; }
__device__ __forceinline__ float ldf(const bf16* p) { return b2f(*p); }
__device__ __forceinline__ void stf(float* p, float v) { *p = v; }
__device__ __forceinline__ void stf(bf16* p, float v) { *p = f2b(v); }
__device__ __forceinline__ float2 ldf2(const float* p) { return *(const float2*)p; }
__device__ __forceinline__ float2 ldf2(const bf16* p) {
    unsigned u = *(const unsigned*)p;
    return make_float2(__uint_as_float(u << 16), __uint_as_float(u & 0xFFFF0000u));
}
__device__ __forceinline__ void stf2(float* p, float a, float b) {
    *(float2*)p = make_float2(a, b);
}
__device__ __forceinline__ void stf2(bf16* p, float a, float b);

__device__ __forceinline__ unsigned pack2bf(float a, float b) {
    unsigned ua = __float_as_uint(a), ub = __float_as_uint(b);
    ua = (ua + 0x7FFFu + ((ua >> 16) & 1u)) >> 16;
    ub = (ub + 0x7FFFu + ((ub >> 16) & 1u)) >> 16;
    return ua | (ub << 16);
}
__device__ __forceinline__ void stf2(bf16* p, float a, float b) {
    *(unsigned*)p = pack2bf(a, b);
}

// 0. sentinel
__global__ __launch_bounds__(256) void k_sentinel(float* out, int n, float val) {
    int i = blockIdx.x * 256 + threadIdx.x;
    if (i < n) out[i] = val;
}

// 2a. histogram of dst
__global__ __launch_bounds__(256) void k_hist(const int* __restrict__ dst,
                                              int* __restrict__ counts, int E) {
    int e = blockIdx.x * 256 + threadIdx.x;
    if (e < E) atomicAdd(&counts[dst[e]], 1);
}

__global__ __launch_bounds__(256) void k_scansum(const int* __restrict__ counts,
                                                 int* __restrict__ btot, int n) {
    __shared__ int sh[256];
    int b = blockIdx.x, t = threadIdx.x;
    int base = b * SCHUNK;
    int s = 0;
#pragma unroll
    for (int k = 0; k < 4; ++k) {
        int i = base + t + k * 256;
        if (i < n) s += counts[i];
    }
    sh[t] = s;
    __syncthreads();
    for (int st = 128; st > 0; st >>= 1) {
        if (t < st) sh[t] += sh[t + st];
        __syncthreads();
    }
    if (t == 0) btot[b] = sh[0];
}

__global__ void k_scansmall(const int* __restrict__ btot, int* __restrict__ boff, int nb) {
    if (threadIdx.x == 0 && blockIdx.x == 0) {
        int a = 0;
        for (int i = 0; i < nb; ++i) { boff[i] = a; a += btot[i]; }
    }
}

// 2b-3. per-chunk scan -> rowptr AND cursor
__global__ __launch_bounds__(256) void k_scanapply(const int* __restrict__ counts,
                                                   const int* __restrict__ boff,
                                                   int* __restrict__ rowptr,
                                                   int* __restrict__ cursor, int n) {
    __shared__ int sh[256];
    int b = blockIdx.x, t = threadIdx.x;
    int base = b * SCHUNK + t * 4;
    int c0 = (base + 0 < n) ? counts[base + 0] : 0;
    int c1 = (base + 1 < n) ? counts[base + 1] : 0;
    int c2 = (base + 2 < n) ? counts[base + 2] : 0;
    int c3 = (base + 3 < n) ? counts[base + 3] : 0;
    int s0 = c0, s1 = s0 + c1, s2 = s1 + c2, s3 = s2 + c3;
    sh[t] = s3;
    __syncthreads();
    for (int st = 1; st < 256; st <<= 1) {
        int v = (t >= st) ? sh[t - st] : 0;
        __syncthreads();
        sh[t] += v;
        __syncthreads();
    }
    int excl = sh[t] - s3 + boff[b];
    if (base + 0 < n) { rowptr[base + 1] = excl + s0; cursor[base + 0] = excl; }
    if (base + 1 < n) { rowptr[base + 2] = excl + s1; cursor[base + 1] = excl + s0; }
    if (base + 2 < n) { rowptr[base + 3] = excl + s2; cursor[base + 2] = excl + s1; }
    if (base + 3 < n) { rowptr[base + 4] = excl + s3; cursor[base + 3] = excl + s2; }
    if (b == 0 && t == 0) rowptr[0] = 0;
}

// 2e. bucket cursors
__global__ void k_binit(const int* __restrict__ rowptr, int* __restrict__ gcur) {
    int b = threadIdx.x;
    if (b < NBUK) gcur[b] = rowptr[b * BDIV];
}

// 2f. pass A: partition edges into ebuf by dst bucket
__global__ __launch_bounds__(256) void k_bucket(const int* __restrict__ src,
                                                const int* __restrict__ dst,
                                                int* __restrict__ gcur,
                                                uint2* __restrict__ ebuf, int E) {
    __shared__ int cnt[NBUK], base[NBUK], off[NBUK];
    int tid = threadIdx.x;
    if (tid < NBUK) { cnt[tid] = 0; off[tid] = 0; }
    __syncthreads();
    int d[4], s[4], bk[4];
    int e0 = blockIdx.x * 1024;
#pragma unroll
    for (int k = 0; k < 4; ++k) {
        int e = e0 + tid + k * 256;
        if (e < E) {
            d[k] = dst[e]; s[k] = src[e];
            bk[k] = d[k] / BDIV;
            atomicAdd(&cnt[bk[k]], 1);
        } else bk[k] = -1;
    }
    __syncthreads();
    if (tid < NBUK && cnt[tid] > 0) base[tid] = atomicAdd(&gcur[tid], cnt[tid]);
    __syncthreads();
#pragma unroll
    for (int k = 0; k < 4; ++k) {
        if (bk[k] >= 0) {
            int sl = base[bk[k]] + atomicAdd(&off[bk[k]], 1);
            ebuf[sl] = make_uint2((unsigned)d[k], (unsigned)s[k]);
        }
    }
}

// 2g. pass B: scatter within buckets
__global__ __launch_bounds__(256) void k_scatter2(const uint2* __restrict__ ebuf,
                                                  const int* __restrict__ rowptr,
                                                  int* __restrict__ cursor,
                                                  int* __restrict__ csr) {
    int bk = blockIdx.x & (NBUK - 1);
    int chunk = blockIdx.x >> 5;
    int lo = rowptr[bk * BDIV];
    int nhi = (bk + 1) * BDIV; if (nhi > NNODES) nhi = NNODES;
    int hi = rowptr[nhi];
    for (int e = lo + chunk * 256 + threadIdx.x; e < hi; e += SC2K * 256) {
        uint2 p = ebuf[e];
        int pos = atomicAdd(&cursor[p.x], 1);
        csr[pos] = (int)p.y;
    }
}

// 3a. pack W of ALL layers into MFMA B-fragment order
__global__ __launch_bounds__(256) void k_packB4(const float* __restrict__ basesW,
                                                const float* __restrict__ combW,
                                                bf16* __restrict__ Bp4) {
    int tid = blockIdx.x * 256 + threadIdx.x;
    if (tid >= LAYERSN * PBL) return;
    int layer = tid / PBL;
    int rem = tid % PBL;
    int l = rem & 63;
    int q = (rem >> 6) & 7;
    int t = rem >> 9;
    int n = t * 16 + (l & 15);
    int k0 = q * 32 + (l >> 4) * 8;
    const float* Wb = basesW + (size_t)layer * HIDC * BFD;
    const float* Wc = combW + (size_t)layer * HIDC * NCOMB;
    short out[8];
#pragma unroll
    for (int i = 0; i < 8; ++i) {
        int k = k0 + i;
        float v = (n < BFD) ? Wb[k * BFD + n] : Wc[k * NCOMB + (n - BFD)];
        unsigned u = __float_as_uint(v);
        out[i] = (short)((u + 0x7FFFu + ((u >> 16) & 1u)) >> 16);
    }
    *(sh8*)(Bp4 + (size_t)tid * 8) = *(sh8*)out;
}

// 3b. MFMA node GEMM (64 rows/block, 4 waves).
//     MODE 0: staging computes AtomEncoder sums from x/emb and WRITES h.
//     MODE 1: staging fuses prev layer's BN-apply+ReLU+residual into h.
template <typename TH, typename TW, int MODE>
__global__ __launch_bounds__(256) void k_gemm_mfma(TH* __restrict__ h,
                                                   const bf16* __restrict__ Bp,
                                                   const float* __restrict__ cb,
                                                   bf16* __restrict__ bases,
                                                   TW* __restrict__ wco,
                                                   const bf16* __restrict__ convp,
                                                   const float* __restrict__ ss,
                                                   const int* __restrict__ x,
                                                   const float* __restrict__ emb) {
    __shared__ unsigned ldsA[8192];
    __shared__ int xsh[64 * NFEAT];
    int tid = threadIdx.x;
    size_t blk = blockIdx.x;
    if (MODE == 0) {
        for (int i = tid; i < 64 * NFEAT; i += 256) {
            int row = i / NFEAT;
            size_t rg = blk * 64 + row;
            xsh[i] = (rg < NNODES) ? x[rg * NFEAT + (i % NFEAT)] : 0;
        }
        __syncthreads();
    }
#pragma unroll 4
    for (int it = 0; it < 32; ++it) {
        int p = tid + it * 256;
        int row = p >> 7, cp = p & 127;
        size_t rg = blk * 64 + row;
        unsigned word = 0;
        if (rg < NNODES) {
            int c0 = cp * 2;
            float a0, a1;
            if (MODE == 0) {
                a0 = 0.f; a1 = 0.f;
#pragma unroll
                for (int f = 0; f < NFEAT; ++f) {
                    const float* ep = emb + ((size_t)(f * VOCABS + xsh[row * NFEAT + f])) * HIDC + c0;
                    float2 ev = *(const float2*)ep;
                    a0 += ev.x; a1 += ev.y;
                }
                stf2(&h[rg * HIDC + c0], a0, a1);
            } else {
                float2 hv = ldf2(&h[rg * HIDC + c0]);
                a0 = hv.x; a1 = hv.y;
                unsigned cu = *(const unsigned*)&convp[rg * HIDC + c0];
                float2 sc = *(const float2*)&ss[c0];
                float2 sb = *(const float2*)&ss[HIDC + c0];
                float v0 = __uint_as_float(cu << 16) * sc.x + sb.x;
                float v1 = __uint_as_float(cu & 0xFFFF0000u) * sc.y + sb.y;
                a0 += fmaxf(v0, 0.f);
                a1 += fmaxf(v1, 0.f);
                stf2(&h[rg * HIDC + c0], a0, a1);
            }
            word = pack2bf(a0, a1);
        }
        ldsA[(row * 128 + cp) ^ ((row & 7) << 2)] = word;
    }
    __syncthreads();
    int w = tid >> 6, l = tid & 63;
    int r = 16 * w + (l & 15);
    sh8 af[8];
    const char* lb = (const char*)ldsA;
#pragma unroll
    for (int q = 0; q < 8; ++q) {
        int byte = (r * 512 + q * 64 + (l >> 4) * 16) ^ ((r & 7) << 4);
        af[q] = *(const sh8*)(lb + byte);
    }
    fx4 acc[NTILES];
#pragma unroll
    for (int t = 0; t < NTILES; ++t) acc[t] = (fx4){0.f, 0.f, 0.f, 0.f};
    const sh8* bp8 = (const sh8*)Bp;
#pragma unroll
    for (int t = 0; t < NTILES; ++t) {
#pragma unroll
        for (int q = 0; q < 8; ++q) {
            acc[t] = __builtin_amdgcn_mfma_f32_16x16x32_bf16(
                af[q], bp8[(t * 8 + q) * 64 + l], acc[t], 0, 0, 0);
        }
    }
#pragma unroll
    for (int t = 0; t < NTILES; ++t) {
#pragma unroll
        for (int j = 0; j < 4; ++j) {
            int rl = 16 * w + (l >> 4) * 4 + j;
            size_t rg = blk * 64 + rl;
            if (rg >= NNODES) continue;
            if (t < 8) {
                int col = t * 16 + (l & 15);
                bases[rg * BFD + col] = f2b(acc[t][j]);
            } else {
                int col = (t - 8) * 16 + (l & 15);
                stf(&wco[rg * NCOMB + col], acc[t][j] + cb[col]);
            }
        }
    }
}

// 4. CSR aggregation + einsum + fused BN-stat partials. v5 (fixed conv stride):
//    one node per 32-lane GROUP (8 nodes/block); lane owns 4 gather channels
//    and 8 output channels; 4 independent gathers in flight; zero shuffles.
template <typename TW>
__global__ __launch_bounds__(256) void k_agg(const int* __restrict__ rowptr,
                                             const int* __restrict__ csr,
                                             const uint2* __restrict__ b2,
                                             const TW* __restrict__ wco,
                                             const float* __restrict__ bias,
                                             bf16* __restrict__ conv,
                                             float* __restrict__ partials) {
    __shared__ float agg[8][3][BFD];
    __shared__ float red[512];
    int tid = threadIdx.x;
    int g = tid >> 5, cl = tid & 31;
    red[tid] = 0.f;
    red[tid + 256] = 0.f;
    __syncthreads();
    int hh = cl >> 2;            // out-channel head group (channels 8cl..8cl+7)
    int dbase = 8 * (cl & 3);    // d = (8cl+j)&31
    float bb[8];
#pragma unroll
    for (int j = 0; j < 8; ++j) bb[j] = bias[8 * cl + j];
    float sts[8], sts2[8];
#pragma unroll
    for (int j = 0; j < 8; ++j) { sts[j] = 0.f; sts2[j] = 0.f; }
    for (int n = blockIdx.x * 8 + g; n < NNODES; n += AGGBLK * 8) {
        int r0 = rowptr[n], r1 = rowptr[n + 1];
        float s0 = 0.f, s1 = 0.f, s2 = 0.f, s3 = 0.f;
        float m0 = -INFINITY, m1 = -INFINITY, m2 = -INFINITY, m3 = -INFINITY;
        int e = r0;
#define ACCU2(v) { float f0 = __uint_as_float((v).x << 16);            \
                   float f1 = __uint_as_float((v).x & 0xFFFF0000u);    \
                   float f2 = __uint_as_float((v).y << 16);            \
                   float f3 = __uint_as_float((v).y & 0xFFFF0000u);    \
                   s0 += f0; s1 += f1; s2 += f2; s3 += f3;             \
                   m0 = fmaxf(m0, f0); m1 = fmaxf(m1, f1);             \
                   m2 = fmaxf(m2, f2); m3 = fmaxf(m3, f3); }
        for (; e + 4 <= r1; e += 4) {
            int i0 = csr[e + 0], i1 = csr[e + 1], i2 = csr[e + 2], i3 = csr[e + 3];
            uint2 v0 = b2[(size_t)i0 * 32 + cl];
            uint2 v1 = b2[(size_t)i1 * 32 + cl];
            uint2 v2 = b2[(size_t)i2 * 32 + cl];
            uint2 v3 = b2[(size_t)i3 * 32 + cl];
            ACCU2(v0) ACCU2(v1) ACCU2(v2) ACCU2(v3)
        }
        for (; e < r1; ++e) {
            uint2 v = b2[(size_t)csr[e] * 32 + cl];
            ACCU2(v)
        }
#undef ACCU2
        float inv = 1.0f / (float)(r1 - r0);
        *(float4*)&agg[g][0][4 * cl] = make_float4(s0, s1, s2, s3);
        *(float4*)&agg[g][1][4 * cl] = make_float4(s0 * inv, s1 * inv, s2 * inv, s3 * inv);
        *(float4*)&agg[g][2][4 * cl] = make_float4(m0, m1, m2, m3);
        // wave-synchronous LDS: same 32 lanes wrote agg[g], now read it
        const TW* wp = &wco[(size_t)n * NCOMB + hh * 12];
        float wv[12];
#pragma unroll
        for (int k = 0; k < 12; ++k) wv[k] = ldf(&wp[k]);
        float o[8];
#pragma unroll
        for (int j = 0; j < 8; ++j) {
            int d = dbase + j;
            float a = 0.f;
#pragma unroll
            for (int b = 0; b < 4; ++b) {
                a += wv[b] * agg[g][0][b * 32 + d];
                a += wv[4 + b] * agg[g][1][b * 32 + d];
                a += wv[8 + b] * agg[g][2][b * 32 + d];
            }
            a += bb[j];
            o[j] = a;
            sts[j] += a;
            sts2[j] += a * a;
        }
        uint4 cv = make_uint4(pack2bf(o[0], o[1]), pack2bf(o[2], o[3]),
                              pack2bf(o[4], o[5]), pack2bf(o[6], o[7]));
        ((uint4*)conv)[(size_t)n * 32 + cl] = cv;   // row = 32 uint4 (FIXED)
    }
#pragma unroll
    for (int j = 0; j < 8; ++j) {
        atomicAdd(&red[8 * cl + j], sts[j]);
        atomicAdd(&red[256 + 8 * cl + j], sts2[j]);
    }
    __syncthreads();
    partials[(size_t)blockIdx.x * 512 + tid] = red[tid];
    partials[(size_t)blockIdx.x * 512 + 256 + tid] = red[tid + 256];
}

// 4b. reduce partials -> sums[512]
__global__ __launch_bounds__(256) void k_redstats(const float* __restrict__ partials,
                                                  float* __restrict__ sums) {
    int g = blockIdx.x * 256 + threadIdx.x;
    int j = g & 511;
    int chunk = g >> 9;
    float s = 0.f;
    for (int pb = chunk * 256; pb < (chunk + 1) * 256; ++pb)
        s += partials[(size_t)pb * 512 + j];
    atomicAdd(&sums[j], s);
}

// 6. BN finalize
template <int C>
__global__ void k_bnfin(const float* __restrict__ sums, const float* __restrict__ g,
                        const float* __restrict__ b, float nrows, float* __restrict__ ss) {
    int c = threadIdx.x;
    float mu = sums[c] / nrows;
    float var = sums[C + c] / nrows - mu * mu;
    float rstd = rsqrtf(fmaxf(var, 0.f) + EPSV);
    float sc = rstd * g[c];
    ss[c] = sc;
    ss[C + c] = b[c] - mu * sc;
}

// 8. pooling with FUSED final-layer BN-apply+ReLU+residual (h is dead after)
template <typename TH>
__global__ __launch_bounds__(256) void k_pool(const TH* __restrict__ h,
                                              const bf16* __restrict__ conv,
                                              const float* __restrict__ ss,
                                              const int* __restrict__ batch,
                                              float* __restrict__ gs,
                                              float* __restrict__ cnt) {
    int c = threadIdx.x;
    float sc = ss[c], sb = ss[HIDC + c];
    int n0 = blockIdx.x * NPP;
    int end = min(n0 + NPP, NNODES);
    float acc = 0.f, ccnt = 0.f;
    int cur = batch[n0];
    for (int n = n0; n < end; ++n) {
        int b = batch[n];
        if (b != cur) {
            atomicAdd(&gs[(size_t)cur * HIDC + c], acc);
            if (c == 0) atomicAdd(&cnt[cur], ccnt);
            acc = 0.f; ccnt = 0.f; cur = b;
        }
        float v = b2f(conv[(size_t)n * HIDC + c]) * sc + sb;
        acc += ldf(&h[(size_t)n * HIDC + c]) + fmaxf(v, 0.f);
        ccnt += 1.f;
    }
    atomicAdd(&gs[(size_t)cur * HIDC + c], acc);
    if (c == 0) atomicAdd(&cnt[cur], ccnt);
}

__global__ __launch_bounds__(256) void k_pooldiv(float* __restrict__ gs,
                                                 const float* __restrict__ cnt) {
    int i = blockIdx.x * 256 + threadIdx.x;
    if (i >= NGR * HIDC) return;
    int ng = i >> 8;
    gs[i] = gs[i] / fmaxf(cnt[ng], 1.0f);
}

// 9. head row-GEMM
template <int K, int C>
__global__ void k_rowgemm(const float* __restrict__ in, const float* __restrict__ W,
                          float* __restrict__ out) {
    int r = blockIdx.x;
    __shared__ float rs[K];
    for (int i = threadIdx.x; i < K; i += C) rs[i] = in[r * K + i];
    __syncthreads();
    int c = threadIdx.x;
    float acc = 0.f;
    for (int k = 0; k < K; ++k) acc += rs[k] * W[k * C + c];
    out[r * C + c] = acc;
}

// 10. head BN stats
template <int C>
__global__ void k_stats(const float* __restrict__ a, int rows, int rpb,
                        float* __restrict__ sums) {
    int c = threadIdx.x;
    int r0 = blockIdx.x * rpb;
    int r1 = min(r0 + rpb, rows);
    float s = 0.f, s2 = 0.f;
    for (int r = r0; r < r1; ++r) {
        float v = a[r * C + c];
        s += v;
        s2 += v * v;
    }
    atomicAdd(&sums[c], s);
    atomicAdd(&sums[C + c], s2);
}

// 11. head BN apply + ReLU
template <int C>
__global__ void k_apply_relu(float* __restrict__ a, const float* __restrict__ ss, int rows) {
    int i = blockIdx.x * 256 + threadIdx.x;
    if (i >= rows * C) return;
    int c = i % C;
    float v = a[i] * ss[c] + ss[C + c];
    a[i] = fmaxf(v, 0.f);
}

// 12. final linear
__global__ __launch_bounds__(256) void k_final(const float* __restrict__ g2,
                                               const float* __restrict__ w3,
                                               const float* __restrict__ b3,
                                               float* __restrict__ out) {
    int r = blockIdx.x * 256 + threadIdx.x;
    if (r >= NGR) return;
    float acc = 0.f;
#pragma unroll
    for (int k = 0; k < 64; ++k) acc += g2[r * 64 + k] * w3[k];
    out[r] = acc + b3[0];
}

static inline size_t alignup(size_t v) { return (v + 255) & ~(size_t)255; }

template <typename TH, typename TW>
static size_t carve_need(int E) {
    size_t off = 0;
    off = alignup(off + (size_t)NNODES * HIDC * sizeof(TH));   // h
    off = alignup(off + (size_t)NNODES * BFD * 2);             // bases bf16
    off = alignup(off + (size_t)NNODES * NCOMB * sizeof(TW));  // wco
    off = alignup(off + (size_t)NNODES * HIDC * 2);            // conv bf16
    off = alignup(off + (size_t)(NNODES + 1) * 4);             // rowptr
    off = alignup(off + (size_t)NNODES * 4);                   // cursor
    off = alignup(off + (size_t)E * 4);                        // csr
    off = alignup(off + (size_t)E * 8);                        // ebuf (pool aliases)
    off = alignup(off + 2 * HIDC * 4);                         // sums
    off = alignup(off + 2 * HIDC * 4);                         // ss
    off = alignup(off + 256 * 4);                              // btot
    off = alignup(off + 256 * 4);                              // boff
    off = alignup(off + 256 * 4);                              // gcur
    off = alignup(off + (size_t)LAYERSN * PBL * 8 * 2);        // Bp4
    off = alignup(off + (size_t)AGGBLK * 512 * 4);             // partials
    return off;
}

template <typename TH, typename TW>
static void run_all(const int* x, const int* esrc, const int* edst, const int* batch,
                    const float* emb, const float* basesW, const float* combW,
                    const float* combB, const float* convB, const float* bnG,
                    const float* bnB, const float* w1, const float* bn1g,
                    const float* bn1b, const float* w2, const float* bn2g,
                    const float* bn2b, const float* w3, const float* b3, int E,
                    float* out, char* base, hipStream_t stream) {
    size_t off = 0;
    TH* h = (TH*)(base + off);       off = alignup(off + (size_t)NNODES * HIDC * sizeof(TH));
    bf16* bases = (bf16*)(base + off); off = alignup(off + (size_t)NNODES * BFD * 2);
    TW* wco = (TW*)(base + off);     off = alignup(off + (size_t)NNODES * NCOMB * sizeof(TW));
    bf16* conv = (bf16*)(base + off); off = alignup(off + (size_t)NNODES * HIDC * 2);
    int* rowptr = (int*)(base + off); off = alignup(off + (size_t)(NNODES + 1) * 4);
    int* cursor = (int*)(base + off); off = alignup(off + (size_t)NNODES * 4);
    int* csr = (int*)(base + off);    off = alignup(off + (size_t)E * 4);
    size_t o_ebuf = off;
    uint2* ebuf = (uint2*)(base + off); off = alignup(off + (size_t)E * 8);
    float* sums = (float*)(base + off); off = alignup(off + 2 * HIDC * 4);
    float* ss = (float*)(base + off);   off = alignup(off + 2 * HIDC * 4);
    int* btot = (int*)(base + off);     off = alignup(off + 256 * 4);
    int* boff = (int*)(base + off);     off = alignup(off + 256 * 4);
    int* gcur = (int*)(base + off);     off = alignup(off + 256 * 4);
    bf16* Bp4 = (bf16*)(base + off);    off = alignup(off + (size_t)LAYERSN * PBL * 8 * 2);
    float* partials = (float*)(base + off); off = alignup(off + (size_t)AGGBLK * 512 * 4);
    // pool/head buffers alias EBUF region (dead after scatter; ~9 MB < E*8)
    size_t po = o_ebuf;
    float* gs = (float*)(base + po);  po = alignup(po + (size_t)NGR * HIDC * 4);
    float* cnt = (float*)(base + po); po = alignup(po + (size_t)NGR * 4);
    float* r1 = (float*)(base + po);  po = alignup(po + (size_t)NGR * 128 * 4);
    float* r2 = (float*)(base + po);  po = alignup(po + (size_t)NGR * 64 * 4);

    const int NB = (NNODES + SCHUNK - 1) / SCHUNK;  // 98
    const int GEMMBLK = (NNODES + 63) / 64;         // 1563

    // once: CSR build (bucketed) + all-layer weight pack
    k_packB4<<<(LAYERSN * PBL + 255) / 256, 256, 0, stream>>>(basesW, combW, Bp4);
    hipMemsetAsync(cursor, 0, (size_t)NNODES * 4, stream);
    k_hist<<<(E + 255) / 256, 256, 0, stream>>>(edst, cursor, E);
    k_scansum<<<NB, 256, 0, stream>>>(cursor, btot, NNODES);
    k_scansmall<<<1, 64, 0, stream>>>(btot, boff, NB);
    k_scanapply<<<NB, 256, 0, stream>>>(cursor, boff, rowptr, cursor, NNODES);
    k_binit<<<1, NBUK, 0, stream>>>(rowptr, gcur);
    k_bucket<<<(E + 1023) / 1024, 256, 0, stream>>>(esrc, edst, gcur, ebuf, E);
    k_scatter2<<<NBUK * SC2K, 256, 0, stream>>>(ebuf, rowptr, cursor, csr);

    for (int l = 0; l < LAYERSN; ++l) {
        hipMemsetAsync(sums, 0, 2 * HIDC * 4, stream);
        if (l == 0) {
            k_gemm_mfma<TH, TW, 0><<<GEMMBLK, 256, 0, stream>>>(
                h, Bp4, combB, bases, wco, nullptr, ss, x, emb);
        } else {
            k_gemm_mfma<TH, TW, 1><<<GEMMBLK, 256, 0, stream>>>(
                h, Bp4 + (size_t)l * PBL * 8, combB + (size_t)l * NCOMB, bases, wco,
                conv, ss, nullptr, nullptr);
        }
        k_agg<TW><<<AGGBLK, 256, 0, stream>>>(rowptr, csr, (const uint2*)bases,
                                              wco, convB + (size_t)l * HIDC, conv,
                                              partials);
        k_redstats<<<16, 256, 0, stream>>>(partials, sums);
        k_bnfin<HIDC><<<1, HIDC, 0, stream>>>(sums, bnG + (size_t)l * HIDC,
                                              bnB + (size_t)l * HIDC, (float)NNODES, ss);
    }

    hipMemsetAsync(gs, 0, (size_t)NGR * HIDC * 4, stream);
    hipMemsetAsync(cnt, 0, (size_t)NGR * 4, stream);
    k_pool<TH><<<(NNODES + NPP - 1) / NPP, 256, 0, stream>>>(h, conv, ss, batch, gs, cnt);
    k_pooldiv<<<(NGR * HIDC + 255) / 256, 256, 0, stream>>>(gs, cnt);

    k_rowgemm<256, 128><<<NGR, 128, 0, stream>>>(gs, w1, r1);
    hipMemsetAsync(sums, 0, 2 * 128 * 4, stream);
    k_stats<128><<<(NGR + 15) / 16, 128, 0, stream>>>(r1, NGR, 16, sums);
    k_bnfin<128><<<1, 128, 0, stream>>>(sums, bn1g, bn1b, (float)NGR, ss);
    k_apply_relu<128><<<(NGR * 128 + 255) / 256, 256, 0, stream>>>(r1, ss, NGR);

    k_rowgemm<128, 64><<<NGR, 64, 0, stream>>>(r1, w2, r2);
    hipMemsetAsync(sums, 0, 2 * 64 * 4, stream);
    k_stats<64><<<(NGR + 31) / 32, 64, 0, stream>>>(r2, NGR, 32, sums);
    k_bnfin<64><<<1, 64, 0, stream>>>(sums, bn2g, bn2b, (float)NGR, ss);
    k_apply_relu<64><<<(NGR * 64 + 255) / 256, 256, 0, stream>>>(r2, ss, NGR);

    k_final<<<(NGR + 255) / 256, 256, 0, stream>>>(r2, w3, b3, out);
}

extern "C" void kernel_launch(void* const* d_in, const int* in_sizes, int n_in,
                              void* d_out, int out_size, void* d_ws, size_t ws_size,
                              hipStream_t stream) {
    const int* x        = (const int*)d_in[0];
    const int* esrc     = (const int*)d_in[1];
    const int* edst     = (const int*)d_in[2];
    const int* batch    = (const int*)d_in[3];
    const float* emb    = (const float*)d_in[4];
    const float* basesW = (const float*)d_in[5];
    const float* combW  = (const float*)d_in[6];
    const float* combB  = (const float*)d_in[7];
    const float* convB  = (const float*)d_in[8];
    const float* bnG    = (const float*)d_in[9];
    const float* bnB    = (const float*)d_in[10];
    const float* w1     = (const float*)d_in[11];
    const float* bn1g   = (const float*)d_in[12];
    const float* bn1b   = (const float*)d_in[13];
    const float* w2     = (const float*)d_in[14];
    const float* bn2g   = (const float*)d_in[15];
    const float* bn2b   = (const float*)d_in[16];
    const float* w3     = (const float*)d_in[17];
    const float* b3     = (const float*)d_in[18];
    const int E = in_sizes[1];

    size_t need_full    = carve_need<float, bf16>(E);   // ~206 MB
    size_t need_compact = carve_need<bf16, bf16>(E);    // ~155 MB

    if (ws_size >= need_full) {
        run_all<float, bf16>(x, esrc, edst, batch, emb, basesW, combW, combB, convB,
                             bnG, bnB, w1, bn1g, bn1b, w2, bn2g, bn2b, w3, b3, E,
                             (float*)d_out, (char*)d_ws, stream);
    } else if (ws_size >= need_compact) {
        run_all<bf16, bf16>(x, esrc, edst, batch, emb, basesW, combW, combB, convB,
                            bnG, bnB, w1, bn1g, bn1b, w2, bn2g, bn2b, w3, b3, E,
                            (float*)d_out, (char*)d_ws, stream);
    } else {
        k_sentinel<<<(out_size + 255) / 256, 256, 0, stream>>>(
            (float*)d_out, out_size, (float)(ws_size >> 20));
    }
}

// Round 13
// 1379.822 us; speedup vs baseline: 1.1444x; 1.0263x over previous
//
#include <hip/hip_runtime.h>
#include <hip/hip_bf16.h>

#define NNODES 100000
#define HIDC 256
#define NFEAT 9
#define VOCABS 128
#define BFD 128        // bases output dim
#define NCOMB 96       // heads*bases*aggs
#define NGR 5000
#define LAYERSN 4
#define EPSV 1e-5f
#define SCHUNK 1024    // scan chunk
#define NPP 16         // nodes per block in pooling
#define NTILES 14      // 224/16 output tiles (8 bases + 6 comb)
#define AGGBLK 2048    // agg grid
#define PBL (NTILES * 8 * 64)   // B fragments per layer
#define NBUK 32        // scatter buckets
#define BDIV 3125      // nodes per bucket
#define SC2K 64        // blocks per bucket in pass B

typedef __hip_bfloat16 bf16;
typedef __attribute__((ext_vector_type(8))) short sh8;
typedef __attribute__((ext_vector_type(4))) float fx4;

__device__ __forceinline__ float b2f(bf16 v) { return __bfloat162float(v); }
__device__ __forceinline__ bf16 f2b(float v) { return __float2bfloat16(v); }
__device__ __forceinline__ float ldf(const float* p) { return *p; }
__device__ __forceinline__ float ldf(const bf16* p) { return b2f(*p); }
__device__ __forceinline__ void stf(float* p, float v) { *p = v; }
__device__ __forceinline__ void stf(bf16* p, float v) { *p = f2b(v); }
__device__ __forceinline__ float2 ldf2(const float* p) { return *(const float2*)p; }
__device__ __forceinline__ float2 ldf2(const bf16* p) {
    unsigned u = *(const unsigned*)p;
    return make_float2(__uint_as_float(u << 16), __uint_as_float(u & 0xFFFF0000u));
}
__device__ __forceinline__ void stf2(float* p, float a, float b) {
    *(float2*)p = make_float2(a, b);
}
__device__ __forceinline__ void stf2(bf16* p, float a, float b);

__device__ __forceinline__ unsigned pack2bf(float a, float b) {
    unsigned ua = __float_as_uint(a), ub = __float_as_uint(b);
    ua = (ua + 0x7FFFu + ((ua >> 16) & 1u)) >> 16;
    ub = (ub + 0x7FFFu + ((ub >> 16) & 1u)) >> 16;
    return ua | (ub << 16);
}
__device__ __forceinline__ void stf2(bf16* p, float a, float b) {
    *(unsigned*)p = pack2bf(a, b);
}

// 0. sentinel
__global__ __launch_bounds__(256) void k_sentinel(float* out, int n, float val) {
    int i = blockIdx.x * 256 + threadIdx.x;
    if (i < n) out[i] = val;
}

// 2a. histogram of dst
__global__ __launch_bounds__(256) void k_hist(const int* __restrict__ dst,
                                              int* __restrict__ counts, int E) {
    int e = blockIdx.x * 256 + threadIdx.x;
    if (e < E) atomicAdd(&counts[dst[e]], 1);
}

__global__ __launch_bounds__(256) void k_scansum(const int* __restrict__ counts,
                                                 int* __restrict__ btot, int n) {
    __shared__ int sh[256];
    int b = blockIdx.x, t = threadIdx.x;
    int base = b * SCHUNK;
    int s = 0;
#pragma unroll
    for (int k = 0; k < 4; ++k) {
        int i = base + t + k * 256;
        if (i < n) s += counts[i];
    }
    sh[t] = s;
    __syncthreads();
    for (int st = 128; st > 0; st >>= 1) {
        if (t < st) sh[t] += sh[t + st];
        __syncthreads();
    }
    if (t == 0) btot[b] = sh[0];
}

__global__ void k_scansmall(const int* __restrict__ btot, int* __restrict__ boff, int nb) {
    if (threadIdx.x == 0 && blockIdx.x == 0) {
        int a = 0;
        for (int i = 0; i < nb; ++i) { boff[i] = a; a += btot[i]; }
    }
}

// 2b-3. per-chunk scan -> rowptr AND cursor
__global__ __launch_bounds__(256) void k_scanapply(const int* __restrict__ counts,
                                                   const int* __restrict__ boff,
                                                   int* __restrict__ rowptr,
                                                   int* __restrict__ cursor, int n) {
    __shared__ int sh[256];
    int b = blockIdx.x, t = threadIdx.x;
    int base = b * SCHUNK + t * 4;
    int c0 = (base + 0 < n) ? counts[base + 0] : 0;
    int c1 = (base + 1 < n) ? counts[base + 1] : 0;
    int c2 = (base + 2 < n) ? counts[base + 2] : 0;
    int c3 = (base + 3 < n) ? counts[base + 3] : 0;
    int s0 = c0, s1 = s0 + c1, s2 = s1 + c2, s3 = s2 + c3;
    sh[t] = s3;
    __syncthreads();
    for (int st = 1; st < 256; st <<= 1) {
        int v = (t >= st) ? sh[t - st] : 0;
        __syncthreads();
        sh[t] += v;
        __syncthreads();
    }
    int excl = sh[t] - s3 + boff[b];
    if (base + 0 < n) { rowptr[base + 1] = excl + s0; cursor[base + 0] = excl; }
    if (base + 1 < n) { rowptr[base + 2] = excl + s1; cursor[base + 1] = excl + s0; }
    if (base + 2 < n) { rowptr[base + 3] = excl + s2; cursor[base + 2] = excl + s1; }
    if (base + 3 < n) { rowptr[base + 4] = excl + s3; cursor[base + 3] = excl + s2; }
    if (b == 0 && t == 0) rowptr[0] = 0;
}

// 2e. bucket cursors
__global__ void k_binit(const int* __restrict__ rowptr, int* __restrict__ gcur) {
    int b = threadIdx.x;
    if (b < NBUK) gcur[b] = rowptr[b * BDIV];
}

// 2f. pass A: partition edges into ebuf by dst bucket
__global__ __launch_bounds__(256) void k_bucket(const int* __restrict__ src,
                                                const int* __restrict__ dst,
                                                int* __restrict__ gcur,
                                                uint2* __restrict__ ebuf, int E) {
    __shared__ int cnt[NBUK], base[NBUK], off[NBUK];
    int tid = threadIdx.x;
    if (tid < NBUK) { cnt[tid] = 0; off[tid] = 0; }
    __syncthreads();
    int d[4], s[4], bk[4];
    int e0 = blockIdx.x * 1024;
#pragma unroll
    for (int k = 0; k < 4; ++k) {
        int e = e0 + tid + k * 256;
        if (e < E) {
            d[k] = dst[e]; s[k] = src[e];
            bk[k] = d[k] / BDIV;
            atomicAdd(&cnt[bk[k]], 1);
        } else bk[k] = -1;
    }
    __syncthreads();
    if (tid < NBUK && cnt[tid] > 0) base[tid] = atomicAdd(&gcur[tid], cnt[tid]);
    __syncthreads();
#pragma unroll
    for (int k = 0; k < 4; ++k) {
        if (bk[k] >= 0) {
            int sl = base[bk[k]] + atomicAdd(&off[bk[k]], 1);
            ebuf[sl] = make_uint2((unsigned)d[k], (unsigned)s[k]);
        }
    }
}

// 2g. pass B: scatter within buckets
__global__ __launch_bounds__(256) void k_scatter2(const uint2* __restrict__ ebuf,
                                                  const int* __restrict__ rowptr,
                                                  int* __restrict__ cursor,
                                                  int* __restrict__ csr) {
    int bk = blockIdx.x & (NBUK - 1);
    int chunk = blockIdx.x >> 5;
    int lo = rowptr[bk * BDIV];
    int nhi = (bk + 1) * BDIV; if (nhi > NNODES) nhi = NNODES;
    int hi = rowptr[nhi];
    for (int e = lo + chunk * 256 + threadIdx.x; e < hi; e += SC2K * 256) {
        uint2 p = ebuf[e];
        int pos = atomicAdd(&cursor[p.x], 1);
        csr[pos] = (int)p.y;
    }
}

// 3a. pack W of ALL layers into MFMA B-fragment order
__global__ __launch_bounds__(256) void k_packB4(const float* __restrict__ basesW,
                                                const float* __restrict__ combW,
                                                bf16* __restrict__ Bp4) {
    int tid = blockIdx.x * 256 + threadIdx.x;
    if (tid >= LAYERSN * PBL) return;
    int layer = tid / PBL;
    int rem = tid % PBL;
    int l = rem & 63;
    int q = (rem >> 6) & 7;
    int t = rem >> 9;
    int n = t * 16 + (l & 15);
    int k0 = q * 32 + (l >> 4) * 8;
    const float* Wb = basesW + (size_t)layer * HIDC * BFD;
    const float* Wc = combW + (size_t)layer * HIDC * NCOMB;
    short out[8];
#pragma unroll
    for (int i = 0; i < 8; ++i) {
        int k = k0 + i;
        float v = (n < BFD) ? Wb[k * BFD + n] : Wc[k * NCOMB + (n - BFD)];
        unsigned u = __float_as_uint(v);
        out[i] = (short)((u + 0x7FFFu + ((u >> 16) & 1u)) >> 16);
    }
    *(sh8*)(Bp4 + (size_t)tid * 8) = *(sh8*)out;
}

// 3b. MFMA node GEMM (64 rows/block, 4 waves).
//     MODE 0: staging computes AtomEncoder sums from x/emb and WRITES h.
//     MODE 1: staging fuses prev layer's BN-apply+ReLU+residual into h.
template <typename TH, typename TW, int MODE>
__global__ __launch_bounds__(256) void k_gemm_mfma(TH* __restrict__ h,
                                                   const bf16* __restrict__ Bp,
                                                   const float* __restrict__ cb,
                                                   bf16* __restrict__ bases,
                                                   TW* __restrict__ wco,
                                                   const bf16* __restrict__ convp,
                                                   const float* __restrict__ ss,
                                                   const int* __restrict__ x,
                                                   const float* __restrict__ emb) {
    __shared__ unsigned ldsA[8192];
    __shared__ int xsh[64 * NFEAT];
    int tid = threadIdx.x;
    size_t blk = blockIdx.x;
    if (MODE == 0) {
        for (int i = tid; i < 64 * NFEAT; i += 256) {
            int row = i / NFEAT;
            size_t rg = blk * 64 + row;
            xsh[i] = (rg < NNODES) ? x[rg * NFEAT + (i % NFEAT)] : 0;
        }
        __syncthreads();
    }
#pragma unroll 4
    for (int it = 0; it < 32; ++it) {
        int p = tid + it * 256;
        int row = p >> 7, cp = p & 127;
        size_t rg = blk * 64 + row;
        unsigned word = 0;
        if (rg < NNODES) {
            int c0 = cp * 2;
            float a0, a1;
            if (MODE == 0) {
                a0 = 0.f; a1 = 0.f;
#pragma unroll
                for (int f = 0; f < NFEAT; ++f) {
                    const float* ep = emb + ((size_t)(f * VOCABS + xsh[row * NFEAT + f])) * HIDC + c0;
                    float2 ev = *(const float2*)ep;
                    a0 += ev.x; a1 += ev.y;
                }
                stf2(&h[rg * HIDC + c0], a0, a1);
            } else {
                float2 hv = ldf2(&h[rg * HIDC + c0]);
                a0 = hv.x; a1 = hv.y;
                unsigned cu = *(const unsigned*)&convp[rg * HIDC + c0];
                float2 sc = *(const float2*)&ss[c0];
                float2 sb = *(const float2*)&ss[HIDC + c0];
                float v0 = __uint_as_float(cu << 16) * sc.x + sb.x;
                float v1 = __uint_as_float(cu & 0xFFFF0000u) * sc.y + sb.y;
                a0 += fmaxf(v0, 0.f);
                a1 += fmaxf(v1, 0.f);
                stf2(&h[rg * HIDC + c0], a0, a1);
            }
            word = pack2bf(a0, a1);
        }
        ldsA[(row * 128 + cp) ^ ((row & 7) << 2)] = word;
    }
    __syncthreads();
    int w = tid >> 6, l = tid & 63;
    int r = 16 * w + (l & 15);
    sh8 af[8];
    const char* lb = (const char*)ldsA;
#pragma unroll
    for (int q = 0; q < 8; ++q) {
        int byte = (r * 512 + q * 64 + (l >> 4) * 16) ^ ((r & 7) << 4);
        af[q] = *(const sh8*)(lb + byte);
    }
    fx4 acc[NTILES];
#pragma unroll
    for (int t = 0; t < NTILES; ++t) acc[t] = (fx4){0.f, 0.f, 0.f, 0.f};
    const sh8* bp8 = (const sh8*)Bp;
#pragma unroll
    for (int t = 0; t < NTILES; ++t) {
#pragma unroll
        for (int q = 0; q < 8; ++q) {
            acc[t] = __builtin_amdgcn_mfma_f32_16x16x32_bf16(
                af[q], bp8[(t * 8 + q) * 64 + l], acc[t], 0, 0, 0);
        }
    }
#pragma unroll
    for (int t = 0; t < NTILES; ++t) {
#pragma unroll
        for (int j = 0; j < 4; ++j) {
            int rl = 16 * w + (l >> 4) * 4 + j;
            size_t rg = blk * 64 + rl;
            if (rg >= NNODES) continue;
            if (t < 8) {
                int col = t * 16 + (l & 15);
                bases[rg * BFD + col] = f2b(acc[t][j]);
            } else {
                int col = (t - 8) * 16 + (l & 15);
                stf(&wco[rg * NCOMB + col], acc[t][j] + cb[col]);
            }
        }
    }
}

// 4. CSR aggregation + einsum + fused BN-stat partials. v6:
//    one node per 32-lane group; 16 lanes cover a 256B row with uint4 loads
//    -> TWO edges per group-load instruction (sub = edge parity); unroll 4
//    pairs = 8 edges in flight; halves combined via shfl_xor(16).
template <typename TW>
__global__ __launch_bounds__(256) void k_agg(const int* __restrict__ rowptr,
                                             const int* __restrict__ csr,
                                             const uint4* __restrict__ b4,
                                             const TW* __restrict__ wco,
                                             const float* __restrict__ bias,
                                             bf16* __restrict__ conv,
                                             float* __restrict__ partials) {
    __shared__ float agg[8][3][BFD];
    __shared__ float red[512];
    int tid = threadIdx.x;
    int g = tid >> 5, cl = tid & 31;
    int sub = cl >> 4;           // which edge of the pair
    int ln16 = cl & 15;          // uint4 slot within the row (8 channels)
    red[tid] = 0.f;
    red[tid + 256] = 0.f;
    __syncthreads();
    int hh = cl >> 2;            // out-channel head group (channels 8cl..8cl+7)
    int dbase = 8 * (cl & 3);
    float bb[8];
#pragma unroll
    for (int j = 0; j < 8; ++j) bb[j] = bias[8 * cl + j];
    float sts[8], sts2[8];
#pragma unroll
    for (int j = 0; j < 8; ++j) { sts[j] = 0.f; sts2[j] = 0.f; }
    for (int n = blockIdx.x * 8 + g; n < NNODES; n += AGGBLK * 8) {
        int r0 = rowptr[n], r1 = rowptr[n + 1];
        float s0 = 0.f, s1 = 0.f, s2 = 0.f, s3 = 0.f;
        float s4 = 0.f, s5 = 0.f, s6 = 0.f, s7 = 0.f;
        float m0 = -INFINITY, m1 = -INFINITY, m2 = -INFINITY, m3 = -INFINITY;
        float m4 = -INFINITY, m5 = -INFINITY, m6 = -INFINITY, m7 = -INFINITY;
        int e = r0;
#define ACCU4(v) { float f0 = __uint_as_float((v).x << 16);            \
                   float f1 = __uint_as_float((v).x & 0xFFFF0000u);    \
                   float f2 = __uint_as_float((v).y << 16);            \
                   float f3 = __uint_as_float((v).y & 0xFFFF0000u);    \
                   float f4 = __uint_as_float((v).z << 16);            \
                   float f5 = __uint_as_float((v).z & 0xFFFF0000u);    \
                   float f6 = __uint_as_float((v).w << 16);            \
                   float f7 = __uint_as_float((v).w & 0xFFFF0000u);    \
                   s0 += f0; s1 += f1; s2 += f2; s3 += f3;             \
                   s4 += f4; s5 += f5; s6 += f6; s7 += f7;             \
                   m0 = fmaxf(m0, f0); m1 = fmaxf(m1, f1);             \
                   m2 = fmaxf(m2, f2); m3 = fmaxf(m3, f3);             \
                   m4 = fmaxf(m4, f4); m5 = fmaxf(m5, f5);             \
                   m6 = fmaxf(m6, f6); m7 = fmaxf(m7, f7); }
        for (; e + 8 <= r1; e += 8) {
            int i0 = csr[e + 0 + sub], i1 = csr[e + 2 + sub];
            int i2 = csr[e + 4 + sub], i3 = csr[e + 6 + sub];
            uint4 v0 = b4[(size_t)i0 * 16 + ln16];
            uint4 v1 = b4[(size_t)i1 * 16 + ln16];
            uint4 v2 = b4[(size_t)i2 * 16 + ln16];
            uint4 v3 = b4[(size_t)i3 * 16 + ln16];
            ACCU4(v0) ACCU4(v1) ACCU4(v2) ACCU4(v3)
        }
        for (; e + 2 <= r1; e += 2) {
            uint4 v = b4[(size_t)csr[e + sub] * 16 + ln16];
            ACCU4(v)
        }
        if (e < r1 && sub == 0) {
            uint4 v = b4[(size_t)csr[e] * 16 + ln16];
            ACCU4(v)
        }
#undef ACCU4
        // combine the two edge-parity halves (lane ^ 16 within the group)
        s0 += __shfl_xor(s0, 16); s1 += __shfl_xor(s1, 16);
        s2 += __shfl_xor(s2, 16); s3 += __shfl_xor(s3, 16);
        s4 += __shfl_xor(s4, 16); s5 += __shfl_xor(s5, 16);
        s6 += __shfl_xor(s6, 16); s7 += __shfl_xor(s7, 16);
        m0 = fmaxf(m0, __shfl_xor(m0, 16)); m1 = fmaxf(m1, __shfl_xor(m1, 16));
        m2 = fmaxf(m2, __shfl_xor(m2, 16)); m3 = fmaxf(m3, __shfl_xor(m3, 16));
        m4 = fmaxf(m4, __shfl_xor(m4, 16)); m5 = fmaxf(m5, __shfl_xor(m5, 16));
        m6 = fmaxf(m6, __shfl_xor(m6, 16)); m7 = fmaxf(m7, __shfl_xor(m7, 16));
        if (sub == 0) {
            float inv = 1.0f / (float)(r1 - r0);
            int cb2 = ln16 * 8;
            *(float4*)&agg[g][0][cb2]     = make_float4(s0, s1, s2, s3);
            *(float4*)&agg[g][0][cb2 + 4] = make_float4(s4, s5, s6, s7);
            *(float4*)&agg[g][1][cb2]     = make_float4(s0 * inv, s1 * inv, s2 * inv, s3 * inv);
            *(float4*)&agg[g][1][cb2 + 4] = make_float4(s4 * inv, s5 * inv, s6 * inv, s7 * inv);
            *(float4*)&agg[g][2][cb2]     = make_float4(m0, m1, m2, m3);
            *(float4*)&agg[g][2][cb2 + 4] = make_float4(m4, m5, m6, m7);
        }
        // wave-synchronous LDS: writes and reads by the same wave, in order
        const TW* wp = &wco[(size_t)n * NCOMB + hh * 12];
        float wv[12];
#pragma unroll
        for (int k = 0; k < 12; ++k) wv[k] = ldf(&wp[k]);
        float o[8];
#pragma unroll
        for (int j = 0; j < 8; ++j) {
            int d = dbase + j;
            float a = 0.f;
#pragma unroll
            for (int b = 0; b < 4; ++b) {
                a += wv[b] * agg[g][0][b * 32 + d];
                a += wv[4 + b] * agg[g][1][b * 32 + d];
                a += wv[8 + b] * agg[g][2][b * 32 + d];
            }
            a += bb[j];
            o[j] = a;
            sts[j] += a;
            sts2[j] += a * a;
        }
        uint4 cv = make_uint4(pack2bf(o[0], o[1]), pack2bf(o[2], o[3]),
                              pack2bf(o[4], o[5]), pack2bf(o[6], o[7]));
        ((uint4*)conv)[(size_t)n * 32 + cl] = cv;
    }
#pragma unroll
    for (int j = 0; j < 8; ++j) {
        atomicAdd(&red[8 * cl + j], sts[j]);
        atomicAdd(&red[256 + 8 * cl + j], sts2[j]);
    }
    __syncthreads();
    partials[(size_t)blockIdx.x * 512 + tid] = red[tid];
    partials[(size_t)blockIdx.x * 512 + 256 + tid] = red[tid + 256];
}

// 4b. reduce partials -> sums[512]
__global__ __launch_bounds__(256) void k_redstats(const float* __restrict__ partials,
                                                  float* __restrict__ sums) {
    int g = blockIdx.x * 256 + threadIdx.x;
    int j = g & 511;
    int chunk = g >> 9;
    float s = 0.f;
    for (int pb = chunk * 256; pb < (chunk + 1) * 256; ++pb)
        s += partials[(size_t)pb * 512 + j];
    atomicAdd(&sums[j], s);
}

// 6. BN finalize
template <int C>
__global__ void k_bnfin(const float* __restrict__ sums, const float* __restrict__ g,
                        const float* __restrict__ b, float nrows, float* __restrict__ ss) {
    int c = threadIdx.x;
    float mu = sums[c] / nrows;
    float var = sums[C + c] / nrows - mu * mu;
    float rstd = rsqrtf(fmaxf(var, 0.f) + EPSV);
    float sc = rstd * g[c];
    ss[c] = sc;
    ss[C + c] = b[c] - mu * sc;
}

// 8. pooling with FUSED final-layer BN-apply+ReLU+residual
template <typename TH>
__global__ __launch_bounds__(256) void k_pool(const TH* __restrict__ h,
                                              const bf16* __restrict__ conv,
                                              const float* __restrict__ ss,
                                              const int* __restrict__ batch,
                                              float* __restrict__ gs,
                                              float* __restrict__ cnt) {
    int c = threadIdx.x;
    float sc = ss[c], sb = ss[HIDC + c];
    int n0 = blockIdx.x * NPP;
    int end = min(n0 + NPP, NNODES);
    float acc = 0.f, ccnt = 0.f;
    int cur = batch[n0];
    for (int n = n0; n < end; ++n) {
        int b = batch[n];
        if (b != cur) {
            atomicAdd(&gs[(size_t)cur * HIDC + c], acc);
            if (c == 0) atomicAdd(&cnt[cur], ccnt);
            acc = 0.f; ccnt = 0.f; cur = b;
        }
        float v = b2f(conv[(size_t)n * HIDC + c]) * sc + sb;
        acc += ldf(&h[(size_t)n * HIDC + c]) + fmaxf(v, 0.f);
        ccnt += 1.f;
    }
    atomicAdd(&gs[(size_t)cur * HIDC + c], acc);
    if (c == 0) atomicAdd(&cnt[cur], ccnt);
}

__global__ __launch_bounds__(256) void k_pooldiv(float* __restrict__ gs,
                                                 const float* __restrict__ cnt) {
    int i = blockIdx.x * 256 + threadIdx.x;
    if (i >= NGR * HIDC) return;
    int ng = i >> 8;
    gs[i] = gs[i] / fmaxf(cnt[ng], 1.0f);
}

// 9. head row-GEMM
template <int K, int C>
__global__ void k_rowgemm(const float* __restrict__ in, const float* __restrict__ W,
                          float* __restrict__ out) {
    int r = blockIdx.x;
    __shared__ float rs[K];
    for (int i = threadIdx.x; i < K; i += C) rs[i] = in[r * K + i];
    __syncthreads();
    int c = threadIdx.x;
    float acc = 0.f;
    for (int k = 0; k < K; ++k) acc += rs[k] * W[k * C + c];
    out[r * C + c] = acc;
}

// 10. head BN stats
template <int C>
__global__ void k_stats(const float* __restrict__ a, int rows, int rpb,
                        float* __restrict__ sums) {
    int c = threadIdx.x;
    int r0 = blockIdx.x * rpb;
    int r1 = min(r0 + rpb, rows);
    float s = 0.f, s2 = 0.f;
    for (int r = r0; r < r1; ++r) {
        float v = a[r * C + c];
        s += v;
        s2 += v * v;
    }
    atomicAdd(&sums[c], s);
    atomicAdd(&sums[C + c], s2);
}

// 11. head BN apply + ReLU
template <int C>
__global__ void k_apply_relu(float* __restrict__ a, const float* __restrict__ ss, int rows) {
    int i = blockIdx.x * 256 + threadIdx.x;
    if (i >= rows * C) return;
    int c = i % C;
    float v = a[i] * ss[c] + ss[C + c];
    a[i] = fmaxf(v, 0.f);
}

// 12. final linear
__global__ __launch_bounds__(256) void k_final(const float* __restrict__ g2,
                                               const float* __restrict__ w3,
                                               const float* __restrict__ b3,
                                               float* __restrict__ out) {
    int r = blockIdx.x * 256 + threadIdx.x;
    if (r >= NGR) return;
    float acc = 0.f;
#pragma unroll
    for (int k = 0; k < 64; ++k) acc += g2[r * 64 + k] * w3[k];
    out[r] = acc + b3[0];
}

static inline size_t alignup(size_t v) { return (v + 255) & ~(size_t)255; }

template <typename TH, typename TW>
static size_t carve_need(int E) {
    size_t off = 0;
    off = alignup(off + (size_t)NNODES * HIDC * sizeof(TH));   // h
    off = alignup(off + (size_t)NNODES * BFD * 2);             // bases bf16
    off = alignup(off + (size_t)NNODES * NCOMB * sizeof(TW));  // wco
    off = alignup(off + (size_t)NNODES * HIDC * 2);            // conv bf16
    off = alignup(off + (size_t)(NNODES + 1) * 4);             // rowptr
    off = alignup(off + (size_t)NNODES * 4);                   // cursor
    off = alignup(off + (size_t)E * 4);                        // csr
    off = alignup(off + (size_t)E * 8);                        // ebuf (pool aliases)
    off = alignup(off + 2 * HIDC * 4);                         // sums
    off = alignup(off + 2 * HIDC * 4);                         // ss
    off = alignup(off + 256 * 4);                              // btot
    off = alignup(off + 256 * 4);                              // boff
    off = alignup(off + 256 * 4);                              // gcur
    off = alignup(off + (size_t)LAYERSN * PBL * 8 * 2);        // Bp4
    off = alignup(off + (size_t)AGGBLK * 512 * 4);             // partials
    return off;
}

template <typename TH, typename TW>
static void run_all(const int* x, const int* esrc, const int* edst, const int* batch,
                    const float* emb, const float* basesW, const float* combW,
                    const float* combB, const float* convB, const float* bnG,
                    const float* bnB, const float* w1, const float* bn1g,
                    const float* bn1b, const float* w2, const float* bn2g,
                    const float* bn2b, const float* w3, const float* b3, int E,
                    float* out, char* base, hipStream_t stream) {
    size_t off = 0;
    TH* h = (TH*)(base + off);       off = alignup(off + (size_t)NNODES * HIDC * sizeof(TH));
    bf16* bases = (bf16*)(base + off); off = alignup(off + (size_t)NNODES * BFD * 2);
    TW* wco = (TW*)(base + off);     off = alignup(off + (size_t)NNODES * NCOMB * sizeof(TW));
    bf16* conv = (bf16*)(base + off); off = alignup(off + (size_t)NNODES * HIDC * 2);
    int* rowptr = (int*)(base + off); off = alignup(off + (size_t)(NNODES + 1) * 4);
    int* cursor = (int*)(base + off); off = alignup(off + (size_t)NNODES * 4);
    int* csr = (int*)(base + off);    off = alignup(off + (size_t)E * 4);
    size_t o_ebuf = off;
    uint2* ebuf = (uint2*)(base + off); off = alignup(off + (size_t)E * 8);
    float* sums = (float*)(base + off); off = alignup(off + 2 * HIDC * 4);
    float* ss = (float*)(base + off);   off = alignup(off + 2 * HIDC * 4);
    int* btot = (int*)(base + off);     off = alignup(off + 256 * 4);
    int* boff = (int*)(base + off);     off = alignup(off + 256 * 4);
    int* gcur = (int*)(base + off);     off = alignup(off + 256 * 4);
    bf16* Bp4 = (bf16*)(base + off);    off = alignup(off + (size_t)LAYERSN * PBL * 8 * 2);
    float* partials = (float*)(base + off); off = alignup(off + (size_t)AGGBLK * 512 * 4);
    // pool/head buffers alias EBUF region (dead after scatter; ~9 MB < E*8)
    size_t po = o_ebuf;
    float* gs = (float*)(base + po);  po = alignup(po + (size_t)NGR * HIDC * 4);
    float* cnt = (float*)(base + po); po = alignup(po + (size_t)NGR * 4);
    float* r1 = (float*)(base + po);  po = alignup(po + (size_t)NGR * 128 * 4);
    float* r2 = (float*)(base + po);  po = alignup(po + (size_t)NGR * 64 * 4);

    const int NB = (NNODES + SCHUNK - 1) / SCHUNK;  // 98
    const int GEMMBLK = (NNODES + 63) / 64;         // 1563

    // once: CSR build (bucketed) + all-layer weight pack
    k_packB4<<<(LAYERSN * PBL + 255) / 256, 256, 0, stream>>>(basesW, combW, Bp4);
    hipMemsetAsync(cursor, 0, (size_t)NNODES * 4, stream);
    k_hist<<<(E + 255) / 256, 256, 0, stream>>>(edst, cursor, E);
    k_scansum<<<NB, 256, 0, stream>>>(cursor, btot, NNODES);
    k_scansmall<<<1, 64, 0, stream>>>(btot, boff, NB);
    k_scanapply<<<NB, 256, 0, stream>>>(cursor, boff, rowptr, cursor, NNODES);
    k_binit<<<1, NBUK, 0, stream>>>(rowptr, gcur);
    k_bucket<<<(E + 1023) / 1024, 256, 0, stream>>>(esrc, edst, gcur, ebuf, E);
    k_scatter2<<<NBUK * SC2K, 256, 0, stream>>>(ebuf, rowptr, cursor, csr);

    for (int l = 0; l < LAYERSN; ++l) {
        hipMemsetAsync(sums, 0, 2 * HIDC * 4, stream);
        if (l == 0) {
            k_gemm_mfma<TH, TW, 0><<<GEMMBLK, 256, 0, stream>>>(
                h, Bp4, combB, bases, wco, nullptr, ss, x, emb);
        } else {
            k_gemm_mfma<TH, TW, 1><<<GEMMBLK, 256, 0, stream>>>(
                h, Bp4 + (size_t)l * PBL * 8, combB + (size_t)l * NCOMB, bases, wco,
                conv, ss, nullptr, nullptr);
        }
        k_agg<TW><<<AGGBLK, 256, 0, stream>>>(rowptr, csr, (const uint4*)bases,
                                              wco, convB + (size_t)l * HIDC, conv,
                                              partials);
        k_redstats<<<16, 256, 0, stream>>>(partials, sums);
        k_bnfin<HIDC><<<1, HIDC, 0, stream>>>(sums, bnG + (size_t)l * HIDC,
                                              bnB + (size_t)l * HIDC, (float)NNODES, ss);
    }

    hipMemsetAsync(gs, 0, (size_t)NGR * HIDC * 4, stream);
    hipMemsetAsync(cnt, 0, (size_t)NGR * 4, stream);
    k_pool<TH><<<(NNODES + NPP - 1) / NPP, 256, 0, stream>>>(h, conv, ss, batch, gs, cnt);
    k_pooldiv<<<(NGR * HIDC + 255) / 256, 256, 0, stream>>>(gs, cnt);

    k_rowgemm<256, 128><<<NGR, 128, 0, stream>>>(gs, w1, r1);
    hipMemsetAsync(sums, 0, 2 * 128 * 4, stream);
    k_stats<128><<<(NGR + 15) / 16, 128, 0, stream>>>(r1, NGR, 16, sums);
    k_bnfin<128><<<1, 128, 0, stream>>>(sums, bn1g, bn1b, (float)NGR, ss);
    k_apply_relu<128><<<(NGR * 128 + 255) / 256, 256, 0, stream>>>(r1, ss, NGR);

    k_rowgemm<128, 64><<<NGR, 64, 0, stream>>>(r1, w2, r2);
    hipMemsetAsync(sums, 0, 2 * 64 * 4, stream);
    k_stats<64><<<(NGR + 31) / 32, 64, 0, stream>>>(r2, NGR, 32, sums);
    k_bnfin<64><<<1, 64, 0, stream>>>(sums, bn2g, bn2b, (float)NGR, ss);
    k_apply_relu<64><<<(NGR * 64 + 255) / 256, 256, 0, stream>>>(r2, ss, NGR);

    k_final<<<(NGR + 255) / 256, 256, 0, stream>>>(r2, w3, b3, out);
}

extern "C" void kernel_launch(void* const* d_in, const int* in_sizes, int n_in,
                              void* d_out, int out_size, void* d_ws, size_t ws_size,
                              hipStream_t stream) {
    const int* x        = (const int*)d_in[0];
    const int* esrc     = (const int*)d_in[1];
    const int* edst     = (const int*)d_in[2];
    const int* batch    = (const int*)d_in[3];
    const float* emb    = (const float*)d_in[4];
    const float* basesW = (const float*)d_in[5];
    const float* combW  = (const float*)d_in[6];
    const float* combB  = (const float*)d_in[7];
    const float* convB  = (const float*)d_in[8];
    const float* bnG    = (const float*)d_in[9];
    const float* bnB    = (const float*)d_in[10];
    const float* w1     = (const float*)d_in[11];
    const float* bn1g   = (const float*)d_in[12];
    const float* bn1b   = (const float*)d_in[13];
    const float* w2     = (const float*)d_in[14];
    const float* bn2g   = (const float*)d_in[15];
    const float* bn2b   = (const float*)d_in[16];
    const float* w3     = (const float*)d_in[17];
    const float* b3     = (const float*)d_in[18];
    const int E = in_sizes[1];

    size_t need_full    = carve_need<float, bf16>(E);   // ~206 MB
    size_t need_compact = carve_need<bf16, bf16>(E);    // ~155 MB

    if (ws_size >= need_full) {
        run_all<float, bf16>(x, esrc, edst, batch, emb, basesW, combW, combB, convB,
                             bnG, bnB, w1, bn1g, bn1b, w2, bn2g, bn2b, w3, b3, E,
                             (float*)d_out, (char*)d_ws, stream);
    } else if (ws_size >= need_compact) {
        run_all<bf16, bf16>(x, esrc, edst, batch, emb, basesW, combW, combB, convB,
                            bnG, bnB, w1, bn1g, bn1b, w2, bn2g, bn2b, w3, b3, E,
                            (float*)d_out, (char*)d_ws, stream);
    } else {
        k_sentinel<<<(out_size + 255) / 256, 256, 0, stream>>>(
            (float*)d_out, out_size, (float)(ws_size >> 20));
    }
}